// Round 5
// baseline (202.160 us; speedup 1.0000x reference)
//
#include <hip/hip_runtime.h>
#include <math.h>

#define BATCH 4
#define CH    256
#define CQK   32
#define NPIX  4096   // 64*64
#define LOG2E 1.4426950408889634f

typedef __attribute__((ext_vector_type(8))) short short8;   // 8 bf16 (4 VGPRs)
typedef __attribute__((ext_vector_type(4))) float f32x4;

static __device__ __forceinline__ unsigned short f2bf(float f) {
    unsigned u = __builtin_bit_cast(unsigned, f);
    u = (u + 0x7fffu + ((u >> 16) & 1u)) >> 16;   // RNE
    return (unsigned short)u;
}
static __device__ __forceinline__ float bf2f(unsigned short s) {
    unsigned u = ((unsigned)s) << 16;
    return __builtin_bit_cast(float, u);
}
static __device__ __forceinline__ float exp2_fast(float x) {
    float r; asm("v_exp_f32 %0, %1" : "=v"(r) : "v"(x)); return r;
}
static __device__ __forceinline__ unsigned cvt_pk_bf16(float lo, float hi) {
    unsigned r; asm("v_cvt_pk_bf16_f32 %0, %1, %2" : "=v"(r) : "v"(lo), "v"(hi)); return r;
}

// ---------------------------------------------------------------------------
// Kernel 0: W -> bf16 hi/lo. Q rows pre-scaled by log2(e) (base-2 softmax).
// ---------------------------------------------------------------------------
__global__ __launch_bounds__(256) void wcvt_kernel(
    const float* __restrict__ wq, const float* __restrict__ wk,
    const float* __restrict__ wv,
    unsigned short* __restrict__ Wh, unsigned short* __restrict__ Wl)
{
    int idx = blockIdx.x * 256 + threadIdx.x;   // 0..81919
    int r = idx >> 8, c = idx & 255;
    float f;
    if (r < 32)       f = wq[r * 256 + c] * LOG2E;
    else if (r < 64)  f = wk[(r - 32) * 256 + c];
    else              f = wv[(r - 64) * 256 + c];
    unsigned short h = f2bf(f);
    Wh[idx] = h;
    Wl[idx] = f2bf(f - bf2f(h));
}

// ---------------------------------------------------------------------------
// Kernel 1: q/k/v projections as compensated-bf16 MFMA GEMM.
// ---------------------------------------------------------------------------
__global__ __launch_bounds__(256) void qkv_kernel(
    const float* __restrict__ x,
    const float* __restrict__ bq, const float* __restrict__ bk,
    const float* __restrict__ bv,
    const unsigned short* __restrict__ Wh, const unsigned short* __restrict__ Wl,
    unsigned short* __restrict__ Qh, unsigned short* __restrict__ Ql,
    unsigned short* __restrict__ Kh, unsigned short* __restrict__ Kl,
    unsigned short* __restrict__ Vb)
{
    __shared__ __align__(16) unsigned short Xh[32 * 256];  // swizzled [n][c]
    __shared__ __align__(16) unsigned short Xl[32 * 256];

    const int b  = blockIdx.y;
    const int n0 = blockIdx.x * 32;
    const int t  = threadIdx.x;

    #pragma unroll
    for (int rep = 0; rep < 8; ++rep) {
        int idx = rep * 256 + t;       // float4 units
        int c = idx >> 3, n4 = idx & 7;
        float4 xv = *(const float4*)&x[((size_t)b * CH + c) * NPIX + n0 + n4 * 4];
        #pragma unroll
        for (int u = 0; u < 4; ++u) {
            int n = n4 * 4 + u;
            float f = (&xv.x)[u];
            unsigned short h = f2bf(f);
            unsigned short l = f2bf(f - bf2f(h));
            int off = n * 512 + (((c >> 3) * 16) ^ ((n & 7) << 4)) + (c & 7) * 2;
            *(unsigned short*)((char*)Xh + off) = h;
            *(unsigned short*)((char*)Xl + off) = l;
        }
    }
    __syncthreads();

    const int w = t >> 6, l = t & 63, g = l >> 4, m = l & 15;

    for (int dt = 0; dt < 5; ++dt) {
        const int d0 = w * 80 + dt * 16;

        short8 wh[8], wl[8];
        #pragma unroll
        for (int ks = 0; ks < 8; ++ks) {
            size_t off = (size_t)(d0 + m) * 256 + ks * 32 + g * 8;
            wh[ks] = __builtin_bit_cast(short8, *(const uint4*)&Wh[off]);
            wl[ks] = __builtin_bit_cast(short8, *(const uint4*)&Wl[off]);
        }

        f32x4 acc[2];
        acc[0] = (f32x4){0.f, 0.f, 0.f, 0.f};
        acc[1] = (f32x4){0.f, 0.f, 0.f, 0.f};
        #pragma unroll
        for (int nt = 0; nt < 2; ++nt) {
            const int n = nt * 16 + m;
            #pragma unroll
            for (int ks = 0; ks < 8; ++ks) {
                int off = n * 512 + (((ks * 4 + g) * 16) ^ ((n & 7) << 4));
                short8 xh = __builtin_bit_cast(short8, *(const uint4*)((char*)Xh + off));
                short8 xl = __builtin_bit_cast(short8, *(const uint4*)((char*)Xl + off));
                acc[nt] = __builtin_amdgcn_mfma_f32_16x16x32_bf16(wh[ks], xh, acc[nt], 0, 0, 0);
                acc[nt] = __builtin_amdgcn_mfma_f32_16x16x32_bf16(wh[ks], xl, acc[nt], 0, 0, 0);
                acc[nt] = __builtin_amdgcn_mfma_f32_16x16x32_bf16(wl[ks], xh, acc[nt], 0, 0, 0);
            }
        }

        int kind;                      // 0=Q, 1=K, 2=V
        float4 bias;
        if (d0 < 32)      { kind = 0; bias = *(const float4*)&bq[d0 + g * 4];
                            bias.x *= LOG2E; bias.y *= LOG2E; bias.z *= LOG2E; bias.w *= LOG2E; }
        else if (d0 < 64) { kind = 1; bias = *(const float4*)&bk[d0 - 32 + g * 4]; }
        else              { kind = 2; bias = *(const float4*)&bv[d0 - 64 + g * 4]; }

        #pragma unroll
        for (int nt = 0; nt < 2; ++nt) {
            const int n = n0 + nt * 16 + m;
            if (kind == 2) {
                const int c0 = d0 - 64;
                #pragma unroll
                for (int r = 0; r < 4; ++r) {
                    float val = acc[nt][r] + (&bias.x)[r];
                    Vb[((size_t)b * CH + c0 + g * 4 + r) * NPIX + n] = f2bf(val);
                }
            } else {
                unsigned short hs[4], ls[4];
                #pragma unroll
                for (int r = 0; r < 4; ++r) {
                    float val = acc[nt][r] + (&bias.x)[r];
                    unsigned short h = f2bf(val);
                    hs[r] = h;
                    ls[r] = f2bf(val - bf2f(h));
                }
                const int dcol = (d0 & 31) + g * 4;
                const size_t base = ((size_t)b * NPIX + n) * CQK + dcol;
                uint2 uh, ul;
                uh.x = (unsigned)hs[0] | ((unsigned)hs[1] << 16);
                uh.y = (unsigned)hs[2] | ((unsigned)hs[3] << 16);
                ul.x = (unsigned)ls[0] | ((unsigned)ls[1] << 16);
                ul.y = (unsigned)ls[2] | ((unsigned)ls[3] << 16);
                if (kind == 0) {
                    *(uint2*)&Qh[base] = uh;
                    *(uint2*)&Ql[base] = ul;
                } else {
                    *(uint2*)&Kh[base] = uh;
                    *(uint2*)&Kl[base] = ul;
                }
            }
        }
    }
}

// ---------------------------------------------------------------------------
// Kernel 2: flash attention, producer/consumer waves + channel-split blocks.
//   Grid 512 = (batch 4) x (i-tile 64) x (channel-half 2). 512 threads.
//   Waves 0-3: producers (QK^T + softmax + P pack) -- identical in both
//     half-blocks (duplicated, keeps softmax wave-local).
//   Waves 4-7: consumers (PV MFMA on 32 channels each + K/V prefetch).
//   2 blocks/CU -> 4 waves/SIMD; independent chains fill barrier stalls.
// ---------------------------------------------------------------------------
__global__ __launch_bounds__(512, 4) void attn_kernel(
    const unsigned short* __restrict__ Qh, const unsigned short* __restrict__ Ql,
    const unsigned short* __restrict__ Kh, const unsigned short* __restrict__ Kl,
    const unsigned short* __restrict__ Vb,
    const float* __restrict__ x, const float* __restrict__ gamma,
    float* __restrict__ out)
{
    __shared__ __align__(16) char Ksw[2][8192];   // K tile [j][hi|lo] swizzled
    __shared__ uint4 Pbuf[2][512];                // P'[64 i][64 j] bf16, swizzled
    __shared__ float sFac[2][64];
    __shared__ float sL[64];

    // XCD swizzle: bid&7 = XCD; batch per XCD-pair; channel-half = pair parity
    const int bid  = blockIdx.x;
    const int b    = (bid & 7) >> 1;
    const int half = bid & 1;
    const int i0   = (bid >> 3) * 64;

    const int t   = threadIdx.x;
    const int wv8 = t >> 6;                  // 0..7
    const bool isProd = (wv8 < 4);
    const int w   = wv8 & 3;                 // role-local wave id
    const int l   = t & 63, g = l >> 4, m = l & 15;
    const int irow = w * 16 + m;

    // ---- cooperative K tile 0 staging: 512 slots, one uint4 per thread ----
    {
        int sj = t >> 3, sq = t & 7;
        const unsigned short* kp = (sq >> 2) ? Kl : Kh;
        int wr = sj * 128 + ((sq * 16) ^ ((sj & 7) << 4));
        *(uint4*)&Ksw[0][wr] =
            *(const uint4*)&kp[((size_t)b * NPIX + sj) * CQK + (sq & 3) * 8];
    }

    // ---- producer state ----
    short8 qh = {}, ql = {};
    float m_run = -1e30f, l_run = 0.f;
    int pwoff[4];
    if (isProd) {
        const int iq = i0 + irow;
        qh = __builtin_bit_cast(short8, *(const uint4*)&Qh[((size_t)b * NPIX + iq) * CQK + g * 8]);
        ql = __builtin_bit_cast(short8, *(const uint4*)&Ql[((size_t)b * NPIX + iq) * CQK + g * 8]);
        #pragma unroll
        for (int jf = 0; jf < 4; ++jf)
            pwoff[jf] = (irow * 128 + jf * 32 + g * 8) ^ ((irow & 7) << 4);
    }

    // ---- consumer state (32 channels per wave: half*128 + w*32) ----
    f32x4 acc[2][4];
    #pragma unroll
    for (int cf = 0; cf < 2; ++cf)
        #pragma unroll
        for (int f = 0; f < 4; ++f) acc[cf][f] = (f32x4){0.f, 0.f, 0.f, 0.f};
    const unsigned short* vbase[2];
    uint4 vcur[4];
    int pr_off[4][2];
    int kwr0 = 0, kwr1 = 0;
    const unsigned short* kpfx = Kh;
    size_t kpf_base = 0;
    if (!isProd) {
        #pragma unroll
        for (int cf = 0; cf < 2; ++cf) {
            vbase[cf] = Vb + ((size_t)b * CH + half * 128 + w * 32 + cf * 16 + m) * NPIX;
            vcur[cf * 2]     = *(const uint4*)&vbase[cf][g * 8];
            vcur[cf * 2 + 1] = *(const uint4*)&vbase[cf][32 + g * 8];
        }
        #pragma unroll
        for (int f = 0; f < 4; ++f) {
            pr_off[f][0] = ((f * 16 + m) * 128 + g * 16)      ^ ((m & 7) << 4);
            pr_off[f][1] = ((f * 16 + m) * 128 + g * 16 + 64) ^ ((m & 7) << 4);
        }
        const int t2 = t & 255;
        const int sj0 = t2 >> 3, sq0 = t2 & 7;
        kpfx = (sq0 >> 2) ? Kl : Kh;
        kpf_base = ((size_t)b * NPIX + sj0) * CQK + (sq0 & 3) * 8;
        kwr0 = sj0 * 128 + ((sq0 * 16) ^ ((sj0 & 7) << 4));
        const int sj1 = sj0 + 32;
        kwr1 = sj1 * 128 + ((sq0 * 16) ^ ((sj1 & 7) << 4));
    }

    __syncthreads();

    for (int jt = 0; jt <= 64; ++jt) {
        const int idx = jt & 1;

        if (isProd && jt < 64) {
            // ---- QK^T (compensated bf16, base-2 scaled) ----
            f32x4 sv[4];
            #pragma unroll
            for (int jf = 0; jf < 4; ++jf) {
                const int j = jf * 16 + m;
                short8 kh = __builtin_bit_cast(short8,
                    *(const uint4*)&Ksw[idx][j * 128 + ((g * 16) ^ ((j & 7) << 4))]);
                short8 kl = __builtin_bit_cast(short8,
                    *(const uint4*)&Ksw[idx][j * 128 + (((4 + g) * 16) ^ ((j & 7) << 4))]);
                f32x4 s = (f32x4){0.f, 0.f, 0.f, 0.f};
                s = __builtin_amdgcn_mfma_f32_16x16x32_bf16(kh, qh, s, 0, 0, 0);
                s = __builtin_amdgcn_mfma_f32_16x16x32_bf16(kh, ql, s, 0, 0, 0);
                s = __builtin_amdgcn_mfma_f32_16x16x32_bf16(kl, qh, s, 0, 0, 0);
                sv[jf] = s;
            }

            // ---- tree max ----
            float s16[16];
            #pragma unroll
            for (int jf = 0; jf < 4; ++jf)
                #pragma unroll
                for (int r = 0; r < 4; ++r) s16[jf * 4 + r] = sv[jf][r];
            float mx[8];
            #pragma unroll
            for (int k = 0; k < 8; ++k) mx[k] = fmaxf(s16[k], s16[k + 8]);
            #pragma unroll
            for (int k = 0; k < 4; ++k) mx[k] = fmaxf(mx[k], mx[k + 4]);
            float tmax = fmaxf(fmaxf(mx[0], mx[2]), fmaxf(mx[1], mx[3]));
            tmax = fmaxf(tmax, __shfl_xor(tmax, 16));
            tmax = fmaxf(tmax, __shfl_xor(tmax, 32));

            // ---- defer-max: keep old max unless it grew by > 11.5 (log2) ----
            const bool keep = (tmax <= m_run + 11.5f);
            const float mt  = keep ? m_run : tmax;
            const float fac = keep ? 1.0f : exp2_fast(m_run - tmax);

            float p[16];
            #pragma unroll
            for (int k = 0; k < 16; ++k) p[k] = exp2_fast(s16[k] - mt);
            float sm[8];
            #pragma unroll
            for (int k = 0; k < 8; ++k) sm[k] = p[k] + p[k + 8];
            #pragma unroll
            for (int k = 0; k < 4; ++k) sm[k] = sm[k] + sm[k + 4];
            float tsum = (sm[0] + sm[2]) + (sm[1] + sm[3]);
            tsum += __shfl_xor(tsum, 16);
            tsum += __shfl_xor(tsum, 32);

            l_run = l_run * fac + tsum;
            m_run = mt;
            if (g == 0) sFac[idx][irow] = fac;

            // ---- pack P -> bf16, swizzled LDS ----
            char* pb = (char*)Pbuf[idx];
            #pragma unroll
            for (int jf = 0; jf < 4; ++jf) {
                uint2 u;
                u.x = cvt_pk_bf16(p[jf * 4 + 0], p[jf * 4 + 1]);
                u.y = cvt_pk_bf16(p[jf * 4 + 2], p[jf * 4 + 3]);
                *(uint2*)(pb + pwoff[jf]) = u;
            }
        } else if (!isProd) {
            const bool doV = (jt >= 1 && jt < 64);
            const bool doK = (jt < 63);

            // ---- issue V loads for NEXT PV (tile jt) ----
            uint4 vnext[4];
            if (doV) {
                #pragma unroll
                for (int cf = 0; cf < 2; ++cf) {
                    vnext[cf * 2]     = *(const uint4*)&vbase[cf][jt * 64 + g * 8];
                    vnext[cf * 2 + 1] = *(const uint4*)&vbase[cf][jt * 64 + 32 + g * 8];
                }
            }
            // ---- issue K loads for tile jt+1 ----
            uint4 pk0, pk1;
            if (doK) {
                const size_t rb = kpf_base + (size_t)(jt + 1) * 64 * CQK;
                pk0 = *(const uint4*)&kpfx[rb];
                pk1 = *(const uint4*)&kpfx[rb + 32 * CQK];
            }

            // ---- PV on tile jt-1 ----
            if (jt >= 1) {
                const char* pb = (const char*)Pbuf[idx ^ 1];
                short8 pf[4][2];
                float  ff[4];
                #pragma unroll
                for (int f = 0; f < 4; ++f) {
                    pf[f][0] = __builtin_bit_cast(short8, *(const uint4*)(pb + pr_off[f][0]));
                    pf[f][1] = __builtin_bit_cast(short8, *(const uint4*)(pb + pr_off[f][1]));
                    ff[f] = sFac[idx ^ 1][f * 16 + m];
                }
                if (!__all(ff[0] == 1.f && ff[1] == 1.f && ff[2] == 1.f && ff[3] == 1.f)) {
                    #pragma unroll
                    for (int cf = 0; cf < 2; ++cf)
                        #pragma unroll
                        for (int f = 0; f < 4; ++f) acc[cf][f] *= ff[f];
                }
                __builtin_amdgcn_s_setprio(1);
                #pragma unroll
                for (int cf = 0; cf < 2; ++cf) {
                    short8 v0 = __builtin_bit_cast(short8, vcur[cf * 2]);
                    short8 v1 = __builtin_bit_cast(short8, vcur[cf * 2 + 1]);
                    #pragma unroll
                    for (int f = 0; f < 4; ++f) {
                        f32x4 a = acc[cf][f];
                        a = __builtin_amdgcn_mfma_f32_16x16x32_bf16(v0, pf[f][0], a, 0, 0, 0);
                        a = __builtin_amdgcn_mfma_f32_16x16x32_bf16(v1, pf[f][1], a, 0, 0, 0);
                        acc[cf][f] = a;
                    }
                }
                __builtin_amdgcn_s_setprio(0);
            }

            // ---- write prefetched K tile ----
            if (doK) {
                *(uint4*)&Ksw[idx ^ 1][kwr0] = pk0;
                *(uint4*)&Ksw[idx ^ 1][kwr1] = pk1;
            }
            if (doV) {
                #pragma unroll
                for (int k = 0; k < 4; ++k) vcur[k] = vnext[k];
            }
        }

        __syncthreads();
    }

    // ---- epilogue ----
    if (isProd) {
        if (g == 0) sL[irow] = l_run;
    }
    __syncthreads();
    if (!isProd) {
        const float gm = gamma[0];
        #pragma unroll
        for (int f = 0; f < 4; ++f) {
            float linv = 1.0f / sL[f * 16 + m];
            #pragma unroll
            for (int cf = 0; cf < 2; ++cf) {
                #pragma unroll
                for (int r = 0; r < 4; ++r) {
                    int c = half * 128 + w * 32 + cf * 16 + g * 4 + r;
                    size_t o = ((size_t)b * CH + c) * NPIX + i0 + f * 16 + m;
                    out[o] = gm * acc[cf][f][r] * linv + x[o];
                }
            }
        }
    }
}

extern "C" void kernel_launch(void* const* d_in, const int* in_sizes, int n_in,
                              void* d_out, int out_size, void* d_ws, size_t ws_size,
                              hipStream_t stream) {
    const float* x     = (const float*)d_in[0];
    const float* wq    = (const float*)d_in[1];
    const float* bq    = (const float*)d_in[2];
    const float* wk    = (const float*)d_in[3];
    const float* bk    = (const float*)d_in[4];
    const float* wv    = (const float*)d_in[5];
    const float* bv    = (const float*)d_in[6];
    const float* gamma = (const float*)d_in[7];
    float* out = (float*)d_out;

    // ws layout (bf16): Qh|Ql|Kh|Kl (1MB each) | Vb (8MB) | Wh|Wl (160KB each)
    unsigned short* base = (unsigned short*)d_ws;
    const size_t qk_sz = (size_t)BATCH * NPIX * CQK;   // 524288
    unsigned short* Qh = base;
    unsigned short* Ql = Qh + qk_sz;
    unsigned short* Kh = Ql + qk_sz;
    unsigned short* Kl = Kh + qk_sz;
    unsigned short* Vb = Kl + qk_sz;
    unsigned short* Wh = Vb + (size_t)BATCH * CH * NPIX;
    unsigned short* Wl = Wh + 320 * 256;

    wcvt_kernel<<<320, 256, 0, stream>>>(wq, wk, wv, Wh, Wl);
    qkv_kernel<<<dim3(128, 4), 256, 0, stream>>>(x, bq, bk, bv, Wh, Wl,
                                                 Qh, Ql, Kh, Kl, Vb);
    attn_kernel<<<512, 512, 0, stream>>>(Qh, Ql, Kh, Kl, Vb, x, gamma, out);
}

// Round 6
// 113.751 us; speedup vs baseline: 1.7772x; 1.7772x over previous
//
#include <hip/hip_runtime.h>
#include <math.h>

#define BATCH 4
#define CH    256
#define CQK   32
#define NPIX  4096   // 64*64
#define NT    32     // KV steps of 128 keys each
#define LOG2E 1.4426950408889634f

typedef __attribute__((ext_vector_type(8))) short short8;   // 8 bf16 (4 VGPRs)
typedef __attribute__((ext_vector_type(4))) float f32x4;

static __device__ __forceinline__ unsigned short f2bf(float f) {
    unsigned u = __builtin_bit_cast(unsigned, f);
    u = (u + 0x7fffu + ((u >> 16) & 1u)) >> 16;   // RNE
    return (unsigned short)u;
}
static __device__ __forceinline__ float bf2f(unsigned short s) {
    unsigned u = ((unsigned)s) << 16;
    return __builtin_bit_cast(float, u);
}
static __device__ __forceinline__ float exp2_fast(float x) {
    float r; asm("v_exp_f32 %0, %1" : "=v"(r) : "v"(x)); return r;
}
static __device__ __forceinline__ unsigned cvt_pk_bf16(float lo, float hi) {
    unsigned r; asm("v_cvt_pk_bf16_f32 %0, %1, %2" : "=v"(r) : "v"(lo), "v"(hi)); return r;
}

// ---------------------------------------------------------------------------
// Kernel 0: W -> bf16 hi/lo. Q rows pre-scaled by log2(e) (base-2 softmax).
// ---------------------------------------------------------------------------
__global__ __launch_bounds__(256) void wcvt_kernel(
    const float* __restrict__ wq, const float* __restrict__ wk,
    const float* __restrict__ wv,
    unsigned short* __restrict__ Wh, unsigned short* __restrict__ Wl)
{
    int idx = blockIdx.x * 256 + threadIdx.x;   // 0..81919
    int r = idx >> 8, c = idx & 255;
    float f;
    if (r < 32)       f = wq[r * 256 + c] * LOG2E;
    else if (r < 64)  f = wk[(r - 32) * 256 + c];
    else              f = wv[(r - 64) * 256 + c];
    unsigned short h = f2bf(f);
    Wh[idx] = h;
    Wl[idx] = f2bf(f - bf2f(h));
}

// ---------------------------------------------------------------------------
// Kernel 1: q/k/v projections as compensated-bf16 MFMA GEMM.
//   Outputs: Qh/Ql (hi/lo), Kh (hi only) [b][n][32]; Vb [b][c][n].
// ---------------------------------------------------------------------------
__global__ __launch_bounds__(256) void qkv_kernel(
    const float* __restrict__ x,
    const float* __restrict__ bq, const float* __restrict__ bk,
    const float* __restrict__ bv,
    const unsigned short* __restrict__ Wh, const unsigned short* __restrict__ Wl,
    unsigned short* __restrict__ Qh, unsigned short* __restrict__ Ql,
    unsigned short* __restrict__ Kh, unsigned short* __restrict__ Vb)
{
    __shared__ __align__(16) unsigned short Xh[32 * 256];  // swizzled [n][c]
    __shared__ __align__(16) unsigned short Xl[32 * 256];

    const int b  = blockIdx.y;
    const int n0 = blockIdx.x * 32;
    const int t  = threadIdx.x;

    #pragma unroll
    for (int rep = 0; rep < 8; ++rep) {
        int idx = rep * 256 + t;       // float4 units
        int c = idx >> 3, n4 = idx & 7;
        float4 xv = *(const float4*)&x[((size_t)b * CH + c) * NPIX + n0 + n4 * 4];
        #pragma unroll
        for (int u = 0; u < 4; ++u) {
            int n = n4 * 4 + u;
            float f = (&xv.x)[u];
            unsigned short h = f2bf(f);
            unsigned short l = f2bf(f - bf2f(h));
            int off = n * 512 + (((c >> 3) * 16) ^ ((n & 7) << 4)) + (c & 7) * 2;
            *(unsigned short*)((char*)Xh + off) = h;
            *(unsigned short*)((char*)Xl + off) = l;
        }
    }
    __syncthreads();

    const int w = t >> 6, l = t & 63, g = l >> 4, m = l & 15;

    for (int dt = 0; dt < 5; ++dt) {
        const int d0 = w * 80 + dt * 16;

        short8 wh[8], wl[8];
        #pragma unroll
        for (int ks = 0; ks < 8; ++ks) {
            size_t off = (size_t)(d0 + m) * 256 + ks * 32 + g * 8;
            wh[ks] = __builtin_bit_cast(short8, *(const uint4*)&Wh[off]);
            wl[ks] = __builtin_bit_cast(short8, *(const uint4*)&Wl[off]);
        }

        f32x4 acc[2];
        acc[0] = (f32x4){0.f, 0.f, 0.f, 0.f};
        acc[1] = (f32x4){0.f, 0.f, 0.f, 0.f};
        #pragma unroll
        for (int nt = 0; nt < 2; ++nt) {
            const int n = nt * 16 + m;
            #pragma unroll
            for (int ks = 0; ks < 8; ++ks) {
                int off = n * 512 + (((ks * 4 + g) * 16) ^ ((n & 7) << 4));
                short8 xh = __builtin_bit_cast(short8, *(const uint4*)((char*)Xh + off));
                short8 xl = __builtin_bit_cast(short8, *(const uint4*)((char*)Xl + off));
                acc[nt] = __builtin_amdgcn_mfma_f32_16x16x32_bf16(wh[ks], xh, acc[nt], 0, 0, 0);
                acc[nt] = __builtin_amdgcn_mfma_f32_16x16x32_bf16(wh[ks], xl, acc[nt], 0, 0, 0);
                acc[nt] = __builtin_amdgcn_mfma_f32_16x16x32_bf16(wl[ks], xh, acc[nt], 0, 0, 0);
            }
        }

        int kind;                      // 0=Q, 1=K, 2=V
        float4 bias;
        if (d0 < 32)      { kind = 0; bias = *(const float4*)&bq[d0 + g * 4];
                            bias.x *= LOG2E; bias.y *= LOG2E; bias.z *= LOG2E; bias.w *= LOG2E; }
        else if (d0 < 64) { kind = 1; bias = *(const float4*)&bk[d0 - 32 + g * 4]; }
        else              { kind = 2; bias = *(const float4*)&bv[d0 - 64 + g * 4]; }

        #pragma unroll
        for (int nt = 0; nt < 2; ++nt) {
            const int n = n0 + nt * 16 + m;
            if (kind == 2) {
                const int c0 = d0 - 64;
                #pragma unroll
                for (int r = 0; r < 4; ++r) {
                    float val = acc[nt][r] + (&bias.x)[r];
                    Vb[((size_t)b * CH + c0 + g * 4 + r) * NPIX + n] = f2bf(val);
                }
            } else {
                float val[4];
                unsigned short hs[4];
                #pragma unroll
                for (int r = 0; r < 4; ++r) {
                    val[r] = acc[nt][r] + (&bias.x)[r];
                    hs[r] = f2bf(val[r]);
                }
                const int dcol = (d0 & 31) + g * 4;
                const size_t base = ((size_t)b * NPIX + n) * CQK + dcol;
                uint2 uh;
                uh.x = (unsigned)hs[0] | ((unsigned)hs[1] << 16);
                uh.y = (unsigned)hs[2] | ((unsigned)hs[3] << 16);
                if (kind == 0) {
                    unsigned short ls[4];
                    #pragma unroll
                    for (int r = 0; r < 4; ++r) ls[r] = f2bf(val[r] - bf2f(hs[r]));
                    uint2 ul;
                    ul.x = (unsigned)ls[0] | ((unsigned)ls[1] << 16);
                    ul.y = (unsigned)ls[2] | ((unsigned)ls[3] << 16);
                    *(uint2*)&Qh[base] = uh;
                    *(uint2*)&Ql[base] = ul;
                } else {
                    *(uint2*)&Kh[base] = uh;
                }
            }
        }
    }
}

// ---------------------------------------------------------------------------
// Kernel 2: flash attention, producer/consumer waves, KVBLK = 128.
//   512 threads: waves 0-3 producers (QK^T 2-mfma compensated + base-2
//   online softmax with __all-gated defer-max + P pack), waves 4-7
//   consumers (PV 64 MFMAs + K prefetch). One barrier per step, 32 steps.
//   K LDS: linear 64B rows (conflict-free contiguous reads).
//   P LDS: [64 i][128 j] bf16, 256B rows, ^(m<<4) swizzle both sides.
// ---------------------------------------------------------------------------
__global__ __launch_bounds__(512, 2) void attn_kernel(
    const unsigned short* __restrict__ Qh, const unsigned short* __restrict__ Ql,
    const unsigned short* __restrict__ Kh, const unsigned short* __restrict__ Vb,
    const float* __restrict__ x, const float* __restrict__ gamma,
    float* __restrict__ out)
{
    __shared__ __align__(16) char Ksw[2][8192];    // K tile: 128 rows x 64B, linear
    __shared__ __align__(16) uint4 Pbuf[2][1024];  // P: 64 rows x 256B, swizzled
    __shared__ float sFac[2][64];
    __shared__ float sL[64];

    // XCD swizzle: 2 XCDs per batch
    const int bid = blockIdx.x;
    const int b   = (bid & 7) >> 1;
    const int it  = (bid >> 3) + ((bid & 1) << 5);
    const int i0  = it * 64;

    const int t   = threadIdx.x;
    const int wv8 = t >> 6;
    const bool isProd = (wv8 < 4);
    const int w   = wv8 & 3;
    const int l   = t & 63, g = l >> 4, m = l & 15;
    const int irow = w * 16 + m;

    // ---- prologue: stage K tile 0 (8KB linear, 512 x uint4) ----
    {
        int sj = t >> 2, sq = t & 3;
        *(uint4*)&Ksw[0][sj * 64 + sq * 16] =
            *(const uint4*)&Kh[((size_t)b * NPIX + sj) * CQK + sq * 8];
    }

    // ---- producer state ----
    short8 qh = {}, ql = {};
    float m_run = -1e30f, l_run = 0.f;
    if (isProd) {
        const int iq = i0 + irow;
        qh = __builtin_bit_cast(short8, *(const uint4*)&Qh[((size_t)b * NPIX + iq) * CQK + g * 8]);
        ql = __builtin_bit_cast(short8, *(const uint4*)&Ql[((size_t)b * NPIX + iq) * CQK + g * 8]);
    }

    // ---- consumer state ----
    f32x4 acc[4][4];
    #pragma unroll
    for (int cf = 0; cf < 4; ++cf)
        #pragma unroll
        for (int f = 0; f < 4; ++f) acc[cf][f] = (f32x4){0.f, 0.f, 0.f, 0.f};
    const unsigned short* vrow[4];
    size_t kpf_base = 0;
    int kwr0 = 0;
    if (!isProd) {
        #pragma unroll
        for (int cf = 0; cf < 4; ++cf)
            vrow[cf] = Vb + ((size_t)b * CH + w * 64 + cf * 16 + m) * NPIX;
        const int t2  = t & 255;
        const int sj0 = t2 >> 2, sq0 = t2 & 3;
        kpf_base = ((size_t)b * NPIX + sj0) * CQK + sq0 * 8;
        kwr0 = sj0 * 64 + sq0 * 16;
    }

    __syncthreads();

    for (int jt = 0; jt <= NT; ++jt) {
        const int idx = jt & 1;

        if (isProd) {
            if (jt < NT) {
                // ---- QK^T: 8 j-tiles x 2 compensated MFMAs ----
                f32x4 sv[8];
                #pragma unroll
                for (int jf = 0; jf < 8; ++jf) {
                    short8 kh8 = __builtin_bit_cast(short8,
                        *(const uint4*)&Ksw[idx][jf * 1024 + m * 64 + g * 16]);
                    f32x4 s = (f32x4){0.f, 0.f, 0.f, 0.f};
                    s = __builtin_amdgcn_mfma_f32_16x16x32_bf16(kh8, qh, s, 0, 0, 0);
                    s = __builtin_amdgcn_mfma_f32_16x16x32_bf16(kh8, ql, s, 0, 0, 0);
                    sv[jf] = s;
                }

                float s32[32];
                #pragma unroll
                for (int jf = 0; jf < 8; ++jf)
                    #pragma unroll
                    for (int r = 0; r < 4; ++r) s32[jf * 4 + r] = sv[jf][r];

                // ---- in-lane tree max ----
                float mx[16];
                #pragma unroll
                for (int k = 0; k < 16; ++k) mx[k] = fmaxf(s32[k], s32[k + 16]);
                #pragma unroll
                for (int k = 0; k < 8; ++k) mx[k] = fmaxf(mx[k], mx[k + 8]);
                #pragma unroll
                for (int k = 0; k < 4; ++k) mx[k] = fmaxf(mx[k], mx[k + 4]);
                float tmax = fmaxf(fmaxf(mx[0], mx[2]), fmaxf(mx[1], mx[3]));

                // ---- gated defer-max: cross-lane max only when vote fails ----
                float fac = 1.0f;
                if (!__all(tmax <= m_run + 11.5f)) {
                    float tc = fmaxf(tmax, __shfl_xor(tmax, 16));
                    tc = fmaxf(tc, __shfl_xor(tc, 32));
                    float mt = fmaxf(m_run, tc);
                    fac = exp2_fast(m_run - mt);
                    m_run = mt;
                }

                float p[32];
                #pragma unroll
                for (int k = 0; k < 32; ++k) p[k] = exp2_fast(s32[k] - m_run);
                float sm[16];
                #pragma unroll
                for (int k = 0; k < 16; ++k) sm[k] = p[k] + p[k + 16];
                #pragma unroll
                for (int k = 0; k < 8; ++k) sm[k] = sm[k] + sm[k + 8];
                #pragma unroll
                for (int k = 0; k < 4; ++k) sm[k] = sm[k] + sm[k + 4];
                float tsum = (sm[0] + sm[2]) + (sm[1] + sm[3]);
                tsum += __shfl_xor(tsum, 16);
                tsum += __shfl_xor(tsum, 32);
                l_run = l_run * fac + tsum;
                if (g == 0) sFac[idx][irow] = fac;

                // ---- pack P -> bf16, swizzled ----
                char* pb = (char*)Pbuf[idx];
                #pragma unroll
                for (int jf = 0; jf < 8; ++jf) {
                    uint2 u;
                    u.x = cvt_pk_bf16(p[jf * 4 + 0], p[jf * 4 + 1]);
                    u.y = cvt_pk_bf16(p[jf * 4 + 2], p[jf * 4 + 3]);
                    *(uint2*)(pb + irow * 256 + ((jf * 32 + g * 8) ^ (m << 4))) = u;
                }
            }
        } else {
            const bool doK = (jt < NT - 1);
            uint4 pk0, pk1;
            if (doK) {
                const size_t rb = kpf_base + (size_t)(jt + 1) * 128 * CQK;
                pk0 = *(const uint4*)&Kh[rb];
                pk1 = *(const uint4*)&Kh[rb + 2048];
            }

            if (jt >= 1) {
                const int jb = (jt - 1) * 128;
                const char* pb = (const char*)Pbuf[idx ^ 1];

                // half A: j in [jb, jb+64)
                uint4 vA[8];
                #pragma unroll
                for (int cf = 0; cf < 4; ++cf) {
                    vA[cf * 2]     = *(const uint4*)&vrow[cf][jb + g * 8];
                    vA[cf * 2 + 1] = *(const uint4*)&vrow[cf][jb + 32 + g * 8];
                }
                short8 pf[4][2];
                #pragma unroll
                for (int f = 0; f < 4; ++f) {
                    #pragma unroll
                    for (int k2 = 0; k2 < 2; ++k2)
                        pf[f][k2] = __builtin_bit_cast(short8, *(const uint4*)(pb +
                            (f * 16 + m) * 256 + ((k2 * 64 + g * 16) ^ (m << 4))));
                }
                // half B loads issued early
                uint4 vB[8];
                #pragma unroll
                for (int cf = 0; cf < 4; ++cf) {
                    vB[cf * 2]     = *(const uint4*)&vrow[cf][jb + 64 + g * 8];
                    vB[cf * 2 + 1] = *(const uint4*)&vrow[cf][jb + 96 + g * 8];
                }

                float ff[4];
                #pragma unroll
                for (int f = 0; f < 4; ++f) ff[f] = sFac[idx ^ 1][f * 16 + m];
                if (!__all(ff[0] == 1.f && ff[1] == 1.f && ff[2] == 1.f && ff[3] == 1.f)) {
                    #pragma unroll
                    for (int cf = 0; cf < 4; ++cf)
                        #pragma unroll
                        for (int f = 0; f < 4; ++f) acc[cf][f] *= ff[f];
                }

                __builtin_amdgcn_s_setprio(1);
                #pragma unroll
                for (int cf = 0; cf < 4; ++cf) {
                    short8 v0 = __builtin_bit_cast(short8, vA[cf * 2]);
                    short8 v1 = __builtin_bit_cast(short8, vA[cf * 2 + 1]);
                    #pragma unroll
                    for (int f = 0; f < 4; ++f) {
                        f32x4 a = acc[cf][f];
                        a = __builtin_amdgcn_mfma_f32_16x16x32_bf16(v0, pf[f][0], a, 0, 0, 0);
                        a = __builtin_amdgcn_mfma_f32_16x16x32_bf16(v1, pf[f][1], a, 0, 0, 0);
                        acc[cf][f] = a;
                    }
                }
                __builtin_amdgcn_s_setprio(0);

                short8 pg[4][2];
                #pragma unroll
                for (int f = 0; f < 4; ++f) {
                    #pragma unroll
                    for (int k2 = 0; k2 < 2; ++k2)
                        pg[f][k2] = __builtin_bit_cast(short8, *(const uint4*)(pb +
                            (f * 16 + m) * 256 + (((k2 + 2) * 64 + g * 16) ^ (m << 4))));
                }
                __builtin_amdgcn_s_setprio(1);
                #pragma unroll
                for (int cf = 0; cf < 4; ++cf) {
                    short8 v0 = __builtin_bit_cast(short8, vB[cf * 2]);
                    short8 v1 = __builtin_bit_cast(short8, vB[cf * 2 + 1]);
                    #pragma unroll
                    for (int f = 0; f < 4; ++f) {
                        f32x4 a = acc[cf][f];
                        a = __builtin_amdgcn_mfma_f32_16x16x32_bf16(v0, pg[f][0], a, 0, 0, 0);
                        a = __builtin_amdgcn_mfma_f32_16x16x32_bf16(v1, pg[f][1], a, 0, 0, 0);
                        acc[cf][f] = a;
                    }
                }
                __builtin_amdgcn_s_setprio(0);
            }

            if (doK) {
                *(uint4*)&Ksw[idx ^ 1][kwr0] = pk0;
                *(uint4*)&Ksw[idx ^ 1][kwr0 + 4096] = pk1;
            }
        }

        __syncthreads();
    }

    // ---- epilogue ----
    if (isProd) {
        if (g == 0) sL[irow] = l_run;
    }
    __syncthreads();
    if (!isProd) {
        const float gm = gamma[0];
        #pragma unroll
        for (int f = 0; f < 4; ++f) {
            float linv = 1.0f / sL[f * 16 + m];
            #pragma unroll
            for (int cf = 0; cf < 4; ++cf) {
                #pragma unroll
                for (int r = 0; r < 4; ++r) {
                    int c = w * 64 + cf * 16 + g * 4 + r;
                    size_t o = ((size_t)b * CH + c) * NPIX + i0 + f * 16 + m;
                    out[o] = gm * acc[cf][f][r] * linv + x[o];
                }
            }
        }
    }
}

extern "C" void kernel_launch(void* const* d_in, const int* in_sizes, int n_in,
                              void* d_out, int out_size, void* d_ws, size_t ws_size,
                              hipStream_t stream) {
    const float* x     = (const float*)d_in[0];
    const float* wq    = (const float*)d_in[1];
    const float* bq    = (const float*)d_in[2];
    const float* wk    = (const float*)d_in[3];
    const float* bk    = (const float*)d_in[4];
    const float* wv    = (const float*)d_in[5];
    const float* bv    = (const float*)d_in[6];
    const float* gamma = (const float*)d_in[7];
    float* out = (float*)d_out;

    // ws layout (bf16): Qh|Ql|Kh (1MB each) | Vb (8MB) | Wh|Wl (160KB each)
    unsigned short* base = (unsigned short*)d_ws;
    const size_t qk_sz = (size_t)BATCH * NPIX * CQK;   // 524288
    unsigned short* Qh = base;
    unsigned short* Ql = Qh + qk_sz;
    unsigned short* Kh = Ql + qk_sz;
    unsigned short* Vb = Kh + qk_sz;
    unsigned short* Wh = Vb + (size_t)BATCH * CH * NPIX;
    unsigned short* Wl = Wh + 320 * 256;

    wcvt_kernel<<<320, 256, 0, stream>>>(wq, wk, wv, Wh, Wl);
    qkv_kernel<<<dim3(128, 4), 256, 0, stream>>>(x, bq, bk, bv, Wh, Wl,
                                                 Qh, Ql, Kh, Vb);
    attn_kernel<<<256, 512, 0, stream>>>(Qh, Ql, Kh, Vb, x, gamma, out);
}